// Round 1
// baseline (813.353 us; speedup 1.0000x reference)
//
#include <hip/hip_runtime.h>
#include <math.h>

#define NN 100000
#define NE 1200000
#define INC 128
#define HIDC 64
#define EPSV 1e-5f

// ---------------- degree / normalization ----------------

__global__ void k_deg_init(float* deg) {
    int i = blockIdx.x * blockDim.x + threadIdx.x;
    if (i < NN) deg[i] = 1.0f;  // self-loop
}

__global__ void k_deg_edges(const int* __restrict__ dst, float* deg) {
    int e = blockIdx.x * blockDim.x + threadIdx.x;
    if (e < NE) atomicAdd(&deg[dst[e]], 1.0f);
}

__global__ void k_dinv(float* deg) {
    int i = blockIdx.x * blockDim.x + threadIdx.x;
    if (i < NN) deg[i] = rsqrtf(fmaxf(deg[i], 1.0f));
}

// ---------------- layer-1 GEMM: x[NN][128] @ W1[128][64] ----------------
// writes h (gather source) and agg init = h * dinv^2 (self-loop term)
__global__ __launch_bounds__(256) void k_gemm1(
    const float* __restrict__ x, const float* __restrict__ W,
    const float* __restrict__ dinv, float* __restrict__ h, float* __restrict__ agg) {
    __shared__ float xs[4][INC];
    int node0 = blockIdx.x * 4;
    int tid = threadIdx.x;
    for (int idx = tid; idx < 4 * INC; idx += 256) {
        int r = idx / INC, k = idx % INC;
        int n = node0 + r;
        xs[r][k] = (n < NN) ? x[(size_t)n * INC + k] : 0.0f;
    }
    __syncthreads();
    int r = tid >> 6, c = tid & 63;
    int node = node0 + r;
    if (node >= NN) return;
    float acc = 0.0f;
#pragma unroll 8
    for (int k = 0; k < INC; ++k) acc += xs[r][k] * W[k * HIDC + c];
    h[(size_t)node * HIDC + c] = acc;
    float di = dinv[node];
    agg[(size_t)node * HIDC + c] = acc * di * di;
}

// ---------------- layer-2 GEMM with fused BN+ReLU on the load ----------------
// agg is read (layer-1 aggregation) and overwritten in place with the
// layer-2 self-loop init; row-local, read happens before the barrier.
__global__ __launch_bounds__(256) void k_gemm2(
    float* agg, const float* __restrict__ W,
    const float* __restrict__ scale, const float* __restrict__ shift,
    const float* __restrict__ dinv, float* __restrict__ h) {
    __shared__ float xs[4][HIDC];
    int node0 = blockIdx.x * 4;
    int tid = threadIdx.x;
    int r = tid >> 6, c = tid & 63;
    int node = node0 + r;
    if (node < NN) {
        float v = agg[(size_t)node * HIDC + c];
        xs[r][c] = fmaxf(v * scale[c] + shift[c], 0.0f);
    } else {
        xs[r][c] = 0.0f;
    }
    __syncthreads();
    if (node >= NN) return;
    float acc = 0.0f;
#pragma unroll 8
    for (int k = 0; k < HIDC; ++k) acc += xs[r][k] * W[k * HIDC + c];
    h[(size_t)node * HIDC + c] = acc;
    float di = dinv[node];
    agg[(size_t)node * HIDC + c] = acc * di * di;
}

// ---------------- edge scatter: one wave per edge, lane = channel ----------------
__global__ __launch_bounds__(256) void k_scatter(
    const int* __restrict__ src, const int* __restrict__ dst,
    const float* __restrict__ h, const float* __restrict__ dinv, float* agg) {
    long long gid = (long long)blockIdx.x * blockDim.x + threadIdx.x;
    int e = (int)(gid >> 6);
    int lane = (int)(gid & 63);
    if (e >= NE) return;
    int s = src[e], d = dst[e];
    float v = h[(size_t)s * HIDC + lane] * (dinv[s] * dinv[d]);
    atomicAdd(&agg[(size_t)d * HIDC + lane], v);
}

// ---------------- BN statistics (per-channel sum / sumsq) ----------------
__global__ __launch_bounds__(256) void k_stats(
    const float* __restrict__ agg, float* gsum, float* gsq) {
    __shared__ float ls[256], lq[256];
    int tid = threadIdx.x;
    int c = tid & 63, r = tid >> 6;
    float s = 0.0f, q = 0.0f;
    for (int n = blockIdx.x * 4 + r; n < NN; n += gridDim.x * 4) {
        float v = agg[(size_t)n * HIDC + c];
        s += v; q += v * v;
    }
    ls[tid] = s; lq[tid] = q;
    __syncthreads();
    if (tid < 64) {
        s = ls[tid] + ls[tid + 64] + ls[tid + 128] + ls[tid + 192];
        q = lq[tid] + lq[tid + 64] + lq[tid + 128] + lq[tid + 192];
        atomicAdd(&gsum[c], s);
        atomicAdd(&gsq[c], q);
    }
}

__global__ void k_bnfin(const float* __restrict__ gsum, const float* __restrict__ gsq,
                        const float* __restrict__ g, const float* __restrict__ be,
                        float* scale, float* shift) {
    int c = threadIdx.x;
    if (c < HIDC) {
        float mu = gsum[c] * (1.0f / NN);
        float var = gsq[c] * (1.0f / NN) - mu * mu;
        float inv = rsqrtf(var + EPSV);
        float sc = g[c] * inv;
        scale[c] = sc;
        shift[c] = be[c] - mu * sc;
    }
}

// ---------------- MLP head with fused BN+ReLU on the load ----------------
__global__ __launch_bounds__(256) void k_mlp(
    const float* __restrict__ agg, const float* __restrict__ scale,
    const float* __restrict__ shift,
    const float* __restrict__ Wm1, const float* __restrict__ bm1,
    const float* __restrict__ Wm2, const float* __restrict__ bm2,
    const float* __restrict__ Wm3, const float* __restrict__ bm3,
    float* __restrict__ out) {
    int n = blockIdx.x * blockDim.x + threadIdx.x;
    if (n >= NN) return;
    float h[HIDC];
#pragma unroll
    for (int c = 0; c < HIDC; ++c)
        h[c] = fmaxf(agg[(size_t)n * HIDC + c] * scale[c] + shift[c], 0.0f);
    float a1[32];
#pragma unroll
    for (int j = 0; j < 32; ++j) {
        float acc = bm1[j];
#pragma unroll
        for (int c = 0; c < HIDC; ++c) acc += h[c] * Wm1[c * 32 + j];
        a1[j] = fmaxf(acc, 0.0f);
    }
    float a2[16];
#pragma unroll
    for (int j = 0; j < 16; ++j) {
        float acc = bm2[j];
#pragma unroll
        for (int c = 0; c < 32; ++c) acc += a1[c] * Wm2[c * 16 + j];
        a2[j] = fmaxf(acc, 0.0f);
    }
    float z = bm3[0];
#pragma unroll
    for (int c = 0; c < 16; ++c) z += a2[c] * Wm3[c];
    out[n] = 1.0f / (1.0f + expf(-z));
}

extern "C" void kernel_launch(void* const* d_in, const int* in_sizes, int n_in,
                              void* d_out, int out_size, void* d_ws, size_t ws_size,
                              hipStream_t stream) {
    const float* x   = (const float*)d_in[0];
    const int*   ei  = (const int*)d_in[1];   // [2, NE] int
    const float* W1  = (const float*)d_in[2];
    // d_in[3] = b1: cancels in BatchNorm (per-channel constant before per-channel mean-subtract)
    const float* g1  = (const float*)d_in[4];
    const float* be1 = (const float*)d_in[5];
    const float* W2  = (const float*)d_in[6];
    // d_in[7] = b2: cancels in BatchNorm
    const float* g2  = (const float*)d_in[8];
    const float* be2 = (const float*)d_in[9];
    const float* Wm1 = (const float*)d_in[10];
    const float* bm1 = (const float*)d_in[11];
    const float* Wm2 = (const float*)d_in[12];
    const float* bm2 = (const float*)d_in[13];
    const float* Wm3 = (const float*)d_in[14];
    const float* bm3 = (const float*)d_in[15];
    float* out = (float*)d_out;

    const int* srcI = ei;
    const int* dstI = ei + NE;

    float* ws    = (float*)d_ws;
    float* dinv  = ws;                              // NN
    float* bufH  = ws + NN;                         // NN*64
    float* bufA  = bufH + (size_t)NN * HIDC;        // NN*64
    float* stats = bufA + (size_t)NN * HIDC;        // 512
    float *sum1 = stats,       *sq1 = stats + 64;
    float *sum2 = stats + 128, *sq2 = stats + 192;
    float *scale1 = stats + 256, *shift1 = stats + 320;
    float *scale2 = stats + 384, *shift2 = stats + 448;

    hipMemsetAsync(stats, 0, 256 * sizeof(float), stream);

    k_deg_init<<<(NN + 255) / 256, 256, 0, stream>>>(dinv);
    k_deg_edges<<<(NE + 255) / 256, 256, 0, stream>>>(dstI, dinv);
    k_dinv<<<(NN + 255) / 256, 256, 0, stream>>>(dinv);

    // layer 1
    k_gemm1<<<(NN + 3) / 4, 256, 0, stream>>>(x, W1, dinv, bufH, bufA);
    k_scatter<<<((long long)NE * 64 + 255) / 256, 256, 0, stream>>>(srcI, dstI, bufH, dinv, bufA);
    k_stats<<<512, 256, 0, stream>>>(bufA, sum1, sq1);
    k_bnfin<<<1, 64, 0, stream>>>(sum1, sq1, g1, be1, scale1, shift1);

    // layer 2 (BN+ReLU of layer-1 fused into GEMM2 loads; agg updated in place)
    k_gemm2<<<(NN + 3) / 4, 256, 0, stream>>>(bufA, W2, scale1, shift1, dinv, bufH);
    k_scatter<<<((long long)NE * 64 + 255) / 256, 256, 0, stream>>>(srcI, dstI, bufH, dinv, bufA);
    k_stats<<<512, 256, 0, stream>>>(bufA, sum2, sq2);
    k_bnfin<<<1, 64, 0, stream>>>(sum2, sq2, g2, be2, scale2, shift2);

    // MLP head (BN+ReLU of layer-2 fused into loads)
    k_mlp<<<(NN + 255) / 256, 256, 0, stream>>>(bufA, scale2, shift2,
                                                Wm1, bm1, Wm2, bm2, Wm3, bm3, out);
}

// Round 2
// 617.038 us; speedup vs baseline: 1.3182x; 1.3182x over previous
//
#include <hip/hip_runtime.h>
#include <math.h>

#define NN 100000
#define NE 1200000
#define INC 128
#define HIDC 64
#define EPSV 1e-5f
#define SCAN_BS 1024
#define NBLK ((NN + SCAN_BS - 1) / SCAN_BS)   // 98

// ---------------- CSR build: count, scan, fill ----------------

__global__ void k_count(const int* __restrict__ dst, int* cnt) {
    int e = blockIdx.x * blockDim.x + threadIdx.x;
    if (e < NE) atomicAdd(&cnt[dst[e]], 1);
}

__global__ __launch_bounds__(256) void k_scan1(const int* __restrict__ cnt, int* bsum) {
    __shared__ int part[256];
    int base = blockIdx.x * SCAN_BS + threadIdx.x * 4;
    int s = 0;
#pragma unroll
    for (int j = 0; j < 4; ++j) { int i = base + j; if (i < NN) s += cnt[i]; }
    part[threadIdx.x] = s;
    __syncthreads();
    for (int off = 128; off > 0; off >>= 1) {
        if (threadIdx.x < off) part[threadIdx.x] += part[threadIdx.x + off];
        __syncthreads();
    }
    if (threadIdx.x == 0) bsum[blockIdx.x] = part[0];
}

__global__ void k_scan2(int* bsum) {   // exclusive scan of NBLK block sums
    __shared__ int s[128];
    int t = threadIdx.x;
    if (t < NBLK) s[t] = bsum[t];
    __syncthreads();
    if (t == 0) {
        int acc = 0;
        for (int i = 0; i < NBLK; ++i) { int v = s[i]; s[i] = acc; acc += v; }
    }
    __syncthreads();
    if (t < NBLK) bsum[t] = s[t];
}

// per-block exclusive scan -> cursor (start offsets); also computes dinv
__global__ __launch_bounds__(256) void k_scan3(const int* __restrict__ cnt,
                                               const int* __restrict__ boff,
                                               int* cursor, float* dinv) {
    __shared__ int part[256];
    int t = threadIdx.x;
    int base = blockIdx.x * SCAN_BS + t * 4;
    int v[4]; int s = 0;
#pragma unroll
    for (int j = 0; j < 4; ++j) { int i = base + j; v[j] = (i < NN) ? cnt[i] : 0; s += v[j]; }
    part[t] = s;
    __syncthreads();
    for (int off = 1; off < 256; off <<= 1) {
        int x = (t >= off) ? part[t - off] : 0;
        __syncthreads();
        part[t] += x;
        __syncthreads();
    }
    int run = boff[blockIdx.x] + part[t] - s;   // exclusive prefix for this thread's 4 elems
#pragma unroll
    for (int j = 0; j < 4; ++j) {
        int i = base + j;
        if (i < NN) {
            cursor[i] = run;
            dinv[i] = rsqrtf((float)v[j] + 1.0f);   // deg = indeg + self-loop
            run += v[j];
        }
    }
}

// fill: advances cursor; after this kernel cursor[d] == segment end of d
__global__ void k_fill(const int* __restrict__ src, const int* __restrict__ dst,
                       int* cursor, int* srcSorted) {
    int e = blockIdx.x * blockDim.x + threadIdx.x;
    if (e < NE) {
        int pos = atomicAdd(&cursor[dst[e]], 1);
        srcSorted[pos] = src[e];
    }
}

// ---------------- layer-1 GEMM: x[NN][128] @ W1[128][64] -> h ----------------
__global__ __launch_bounds__(256) void k_gemm1(
    const float* __restrict__ x, const float* __restrict__ W,
    float* __restrict__ h) {
    __shared__ float xs[4][INC];
    int node0 = blockIdx.x * 4;
    int tid = threadIdx.x;
    for (int idx = tid; idx < 4 * INC; idx += 256) {
        int r = idx / INC, k = idx % INC;
        int n = node0 + r;
        xs[r][k] = (n < NN) ? x[(size_t)n * INC + k] : 0.0f;
    }
    __syncthreads();
    int r = tid >> 6, c = tid & 63;
    int node = node0 + r;
    if (node >= NN) return;
    float acc = 0.0f;
#pragma unroll 8
    for (int k = 0; k < INC; ++k) acc += xs[r][k] * W[k * HIDC + c];
    h[(size_t)node * HIDC + c] = acc;
}

// ---------------- layer-2 GEMM with fused BN+ReLU on the load ----------------
__global__ __launch_bounds__(256) void k_gemm2(
    const float* __restrict__ agg, const float* __restrict__ W,
    const float* __restrict__ scale, const float* __restrict__ shift,
    float* __restrict__ h) {
    __shared__ float xs[4][HIDC];
    int node0 = blockIdx.x * 4;
    int tid = threadIdx.x;
    int r = tid >> 6, c = tid & 63;
    int node = node0 + r;
    if (node < NN) {
        float v = agg[(size_t)node * HIDC + c];
        xs[r][c] = fmaxf(v * scale[c] + shift[c], 0.0f);
    } else {
        xs[r][c] = 0.0f;
    }
    __syncthreads();
    if (node >= NN) return;
    float acc = 0.0f;
#pragma unroll 8
    for (int k = 0; k < HIDC; ++k) acc += xs[r][k] * W[k * HIDC + c];
    h[(size_t)node * HIDC + c] = acc;
}

// ---------------- CSR gather: one wave per node, lane = channel ----------------
__global__ __launch_bounds__(256) void k_gather(
    const int* __restrict__ eend, const int* __restrict__ srcSorted,
    const float* __restrict__ dinv, const float* __restrict__ h,
    float* __restrict__ agg) {
    int wid = threadIdx.x >> 6, lane = threadIdx.x & 63;
    int n = blockIdx.x * 4 + wid;
    if (n >= NN) return;
    int beg = n ? eend[n - 1] : 0;
    int end = eend[n];
    float dn = dinv[n];
    float acc = dn * h[(size_t)n * HIDC + lane];   // self-loop term
    for (int i = beg; i < end; ++i) {
        int s = srcSorted[i];
        acc += dinv[s] * h[(size_t)s * HIDC + lane];
    }
    agg[(size_t)n * HIDC + lane] = dn * acc;
}

// ---------------- BN statistics ----------------
__global__ __launch_bounds__(256) void k_stats(
    const float* __restrict__ agg, float* gsum, float* gsq) {
    __shared__ float ls[256], lq[256];
    int tid = threadIdx.x;
    int c = tid & 63, r = tid >> 6;
    float s = 0.0f, q = 0.0f;
    for (int n = blockIdx.x * 4 + r; n < NN; n += gridDim.x * 4) {
        float v = agg[(size_t)n * HIDC + c];
        s += v; q += v * v;
    }
    ls[tid] = s; lq[tid] = q;
    __syncthreads();
    if (tid < 64) {
        s = ls[tid] + ls[tid + 64] + ls[tid + 128] + ls[tid + 192];
        q = lq[tid] + lq[tid + 64] + lq[tid + 128] + lq[tid + 192];
        atomicAdd(&gsum[c], s);
        atomicAdd(&gsq[c], q);
    }
}

__global__ void k_bnfin(const float* __restrict__ gsum, const float* __restrict__ gsq,
                        const float* __restrict__ g, const float* __restrict__ be,
                        float* scale, float* shift) {
    int c = threadIdx.x;
    if (c < HIDC) {
        float mu = gsum[c] * (1.0f / NN);
        float var = gsq[c] * (1.0f / NN) - mu * mu;
        float inv = rsqrtf(var + EPSV);
        float sc = g[c] * inv;
        scale[c] = sc;
        shift[c] = be[c] - mu * sc;
    }
}

// ---------------- MLP head with fused BN+ReLU on the load ----------------
__global__ __launch_bounds__(256) void k_mlp(
    const float* __restrict__ agg, const float* __restrict__ scale,
    const float* __restrict__ shift,
    const float* __restrict__ Wm1, const float* __restrict__ bm1,
    const float* __restrict__ Wm2, const float* __restrict__ bm2,
    const float* __restrict__ Wm3, const float* __restrict__ bm3,
    float* __restrict__ out) {
    int n = blockIdx.x * blockDim.x + threadIdx.x;
    if (n >= NN) return;
    float h[HIDC];
#pragma unroll
    for (int c = 0; c < HIDC; ++c)
        h[c] = fmaxf(agg[(size_t)n * HIDC + c] * scale[c] + shift[c], 0.0f);
    float a1[32];
#pragma unroll
    for (int j = 0; j < 32; ++j) {
        float acc = bm1[j];
#pragma unroll
        for (int c = 0; c < HIDC; ++c) acc += h[c] * Wm1[c * 32 + j];
        a1[j] = fmaxf(acc, 0.0f);
    }
    float a2[16];
#pragma unroll
    for (int j = 0; j < 16; ++j) {
        float acc = bm2[j];
#pragma unroll
        for (int c = 0; c < 32; ++c) acc += a1[c] * Wm2[c * 16 + j];
        a2[j] = fmaxf(acc, 0.0f);
    }
    float z = bm3[0];
#pragma unroll
    for (int c = 0; c < 16; ++c) z += a2[c] * Wm3[c];
    out[n] = 1.0f / (1.0f + expf(-z));
}

extern "C" void kernel_launch(void* const* d_in, const int* in_sizes, int n_in,
                              void* d_out, int out_size, void* d_ws, size_t ws_size,
                              hipStream_t stream) {
    const float* x   = (const float*)d_in[0];
    const int*   ei  = (const int*)d_in[1];   // [2, NE]
    const float* W1  = (const float*)d_in[2];
    // b1 (d_in[3]) cancels in BatchNorm
    const float* g1  = (const float*)d_in[4];
    const float* be1 = (const float*)d_in[5];
    const float* W2  = (const float*)d_in[6];
    // b2 (d_in[7]) cancels in BatchNorm
    const float* g2  = (const float*)d_in[8];
    const float* be2 = (const float*)d_in[9];
    const float* Wm1 = (const float*)d_in[10];
    const float* bm1 = (const float*)d_in[11];
    const float* Wm2 = (const float*)d_in[12];
    const float* bm2 = (const float*)d_in[13];
    const float* Wm3 = (const float*)d_in[14];
    const float* bm3 = (const float*)d_in[15];
    float* out = (float*)d_out;

    const int* srcI = ei;
    const int* dstI = ei + NE;

    int*   cnt       = (int*)d_ws;                      // NN
    int*   bsum      = cnt + NN;                        // 128 (NBLK=98)
    int*   cursor    = bsum + 128;                      // NN  (start offsets -> end offsets after fill)
    int*   srcSorted = cursor + NN;                     // NE
    float* dinv      = (float*)(srcSorted + NE);        // NN
    float* bufH      = dinv + NN;                       // NN*64
    float* bufA      = bufH + (size_t)NN * HIDC;        // NN*64
    float* stats     = bufA + (size_t)NN * HIDC;        // 512
    float *sum1 = stats,       *sq1 = stats + 64;
    float *sum2 = stats + 128, *sq2 = stats + 192;
    float *scale1 = stats + 256, *shift1 = stats + 320;
    float *scale2 = stats + 384, *shift2 = stats + 448;

    hipMemsetAsync(cnt, 0, NN * sizeof(int), stream);
    hipMemsetAsync(stats, 0, 256 * sizeof(float), stream);

    // CSR build (by destination)
    k_count<<<(NE + 255) / 256, 256, 0, stream>>>(dstI, cnt);
    k_scan1<<<NBLK, 256, 0, stream>>>(cnt, bsum);
    k_scan2<<<1, 128, 0, stream>>>(bsum);
    k_scan3<<<NBLK, 256, 0, stream>>>(cnt, bsum, cursor, dinv);
    k_fill<<<(NE + 255) / 256, 256, 0, stream>>>(srcI, dstI, cursor, srcSorted);

    // layer 1
    k_gemm1<<<(NN + 3) / 4, 256, 0, stream>>>(x, W1, bufH);
    k_gather<<<(NN + 3) / 4, 256, 0, stream>>>(cursor, srcSorted, dinv, bufH, bufA);
    k_stats<<<512, 256, 0, stream>>>(bufA, sum1, sq1);
    k_bnfin<<<1, 64, 0, stream>>>(sum1, sq1, g1, be1, scale1, shift1);

    // layer 2
    k_gemm2<<<(NN + 3) / 4, 256, 0, stream>>>(bufA, W2, scale1, shift1, bufH);
    k_gather<<<(NN + 3) / 4, 256, 0, stream>>>(cursor, srcSorted, dinv, bufH, bufA);
    k_stats<<<512, 256, 0, stream>>>(bufA, sum2, sq2);
    k_bnfin<<<1, 64, 0, stream>>>(sum2, sq2, g2, be2, scale2, shift2);

    // MLP head
    k_mlp<<<(NN + 255) / 256, 256, 0, stream>>>(bufA, scale2, shift2,
                                                Wm1, bm1, Wm2, bm2, Wm3, bm3, out);
}